// Round 1
// baseline (5083.091 us; speedup 1.0000x reference)
//
#include <hip/hip_runtime.h>

#define N_PTS 1024
#define BATCH 4
#define HID   64
#define BLOCK 256

__global__ __launch_bounds__(BLOCK) void inet_fp32_kernel(
    const float* __restrict__ pos, const float* __restrict__ vel,
    const float* __restrict__ W1, const float* __restrict__ b1,
    const float* __restrict__ W2, const float* __restrict__ b2,
    const float* __restrict__ W3, const float* __restrict__ b3,
    float* __restrict__ out)
{
    // LDS-staged weights. float4 layout so the hot loop uses ds_read_b128.
    __shared__ float4 sW1[6][16];   // W1[k][g]   k<6, g<64
    __shared__ float4 sB1[16];
    __shared__ float4 sW2[64][16];  // W2[h][g]
    __shared__ float4 sB2[16];
    __shared__ float4 sW3[64];      // W3[g][0..2], .w = pad
    __shared__ float  sB3[3];
    __shared__ float  red[12];      // 4 waves x 3 comps

    const int tid = threadIdx.x;

    for (int idx = tid; idx < 6 * 64; idx += BLOCK) ((float*)sW1)[idx] = W1[idx];
    for (int idx = tid; idx < 64;     idx += BLOCK) ((float*)sB1)[idx] = b1[idx];
    for (int idx = tid; idx < 64 * 64; idx += BLOCK) ((float*)sW2)[idx] = W2[idx];
    for (int idx = tid; idx < 64;     idx += BLOCK) ((float*)sB2)[idx] = b2[idx];
    for (int idx = tid; idx < 64;     idx += BLOCK)
        sW3[idx] = make_float4(W3[idx * 3 + 0], W3[idx * 3 + 1], W3[idx * 3 + 2], 0.f);
    if (tid < 3) sB3[tid] = b3[tid];
    __syncthreads();

    const int b = blockIdx.x / N_PTS;
    const int i = blockIdx.x % N_PTS;

    const float pix = pos[(b * N_PTS + i) * 3 + 0];
    const float piy = pos[(b * N_PTS + i) * 3 + 1];
    const float piz = pos[(b * N_PTS + i) * 3 + 2];
    const float vix = vel[(b * N_PTS + i) * 3 + 0];
    const float viy = vel[(b * N_PTS + i) * 3 + 1];
    const float viz = vel[(b * N_PTS + i) * 3 + 2];

    float f0 = 0.f, f1 = 0.f, f2 = 0.f;

    for (int j = tid; j < N_PTS; j += BLOCK) {
        float x[6];
        x[0] = pos[(b * N_PTS + j) * 3 + 0] - pix;
        x[1] = pos[(b * N_PTS + j) * 3 + 1] - piy;
        x[2] = pos[(b * N_PTS + j) * 3 + 2] - piz;
        x[3] = vel[(b * N_PTS + j) * 3 + 0] - vix;
        x[4] = vel[(b * N_PTS + j) * 3 + 1] - viy;
        x[5] = vel[(b * N_PTS + j) * 3 + 2] - viz;

        // acc_i = 0.5 * sum_j [ MLP(x_ij) - MLP(-x_ij) ]
        for (int s = 0; s < 2; ++s) {
            const float sg = (s == 0) ? 1.f : -1.f;
            float xs[6];
            #pragma unroll
            for (int k = 0; k < 6; ++k) xs[k] = sg * x[k];

            // ---- layer 1: h1 = relu(x*W1 + b1), h1 kept in VGPRs ----
            float h1[64];
            #pragma unroll
            for (int g4 = 0; g4 < 16; ++g4) {
                float4 a = sB1[g4];
                #pragma unroll
                for (int k = 0; k < 6; ++k) {
                    float4 w = sW1[k][g4];
                    a.x = fmaf(xs[k], w.x, a.x);
                    a.y = fmaf(xs[k], w.y, a.y);
                    a.z = fmaf(xs[k], w.z, a.z);
                    a.w = fmaf(xs[k], w.w, a.w);
                }
                h1[g4 * 4 + 0] = fmaxf(a.x, 0.f);
                h1[g4 * 4 + 1] = fmaxf(a.y, 0.f);
                h1[g4 * 4 + 2] = fmaxf(a.z, 0.f);
                h1[g4 * 4 + 3] = fmaxf(a.w, 0.f);
            }

            // ---- layer 2 + layer 3 fused per 4-wide g tile ----
            float fo0 = sB3[0], fo1 = sB3[1], fo2 = sB3[2];
            for (int g4 = 0; g4 < 16; ++g4) {   // runtime loop; h unrolled
                float4 a = sB2[g4];
                #pragma unroll
                for (int h = 0; h < 64; ++h) {  // ds_read_b128 w/ imm offsets
                    float4 w = sW2[h][g4];
                    a.x = fmaf(h1[h], w.x, a.x);
                    a.y = fmaf(h1[h], w.y, a.y);
                    a.z = fmaf(h1[h], w.z, a.z);
                    a.w = fmaf(h1[h], w.w, a.w);
                }
                a.x = fmaxf(a.x, 0.f);
                a.y = fmaxf(a.y, 0.f);
                a.z = fmaxf(a.z, 0.f);
                a.w = fmaxf(a.w, 0.f);
                float4 w0 = sW3[g4 * 4 + 0];
                float4 w1 = sW3[g4 * 4 + 1];
                float4 w2 = sW3[g4 * 4 + 2];
                float4 w3 = sW3[g4 * 4 + 3];
                fo0 = fmaf(a.x, w0.x, fo0); fo1 = fmaf(a.x, w0.y, fo1); fo2 = fmaf(a.x, w0.z, fo2);
                fo0 = fmaf(a.y, w1.x, fo0); fo1 = fmaf(a.y, w1.y, fo1); fo2 = fmaf(a.y, w1.z, fo2);
                fo0 = fmaf(a.z, w2.x, fo0); fo1 = fmaf(a.z, w2.y, fo1); fo2 = fmaf(a.z, w2.z, fo2);
                fo0 = fmaf(a.w, w3.x, fo0); fo1 = fmaf(a.w, w3.y, fo1); fo2 = fmaf(a.w, w3.z, fo2);
            }
            f0 += sg * fo0;
            f1 += sg * fo1;
            f2 += sg * fo2;
        }
    }

    // block reduction: wave shuffle, then LDS across the 4 waves
    #pragma unroll
    for (int off = 32; off > 0; off >>= 1) {
        f0 += __shfl_down(f0, off, 64);
        f1 += __shfl_down(f1, off, 64);
        f2 += __shfl_down(f2, off, 64);
    }
    const int wave = tid >> 6;
    const int lane = tid & 63;
    if (lane == 0) {
        red[wave * 3 + 0] = f0;
        red[wave * 3 + 1] = f1;
        red[wave * 3 + 2] = f2;
    }
    __syncthreads();
    if (tid == 0) {
        float r0 = red[0] + red[3] + red[6] + red[9];
        float r1 = red[1] + red[4] + red[7] + red[10];
        float r2 = red[2] + red[5] + red[8] + red[11];
        out[(b * N_PTS + i) * 3 + 0] = 0.5f * r0;
        out[(b * N_PTS + i) * 3 + 1] = 0.5f * r1;
        out[(b * N_PTS + i) * 3 + 2] = 0.5f * r2;
    }
}

extern "C" void kernel_launch(void* const* d_in, const int* in_sizes, int n_in,
                              void* d_out, int out_size, void* d_ws, size_t ws_size,
                              hipStream_t stream) {
    const float* pos = (const float*)d_in[0];
    const float* vel = (const float*)d_in[1];
    const float* W1  = (const float*)d_in[2];
    const float* b1  = (const float*)d_in[3];
    const float* W2  = (const float*)d_in[4];
    const float* b2  = (const float*)d_in[5];
    const float* W3  = (const float*)d_in[6];
    const float* b3  = (const float*)d_in[7];
    float* out = (float*)d_out;

    dim3 grid(BATCH * N_PTS);
    dim3 block(BLOCK);
    inet_fp32_kernel<<<grid, block, 0, stream>>>(pos, vel, W1, b1, W2, b2, W3, b3, out);
}

// Round 2
// 160.564 us; speedup vs baseline: 31.6578x; 31.6578x over previous
//
#include <hip/hip_runtime.h>

#define NB   4
#define NPTS 1024
#define HID  64

typedef float f32x4  __attribute__((ext_vector_type(4)));
typedef short bf16x8 __attribute__((ext_vector_type(8)));

__device__ inline short f2bf(float x) {
    union { float f; unsigned u; } v; v.f = x;
    unsigned r = (v.u + 0x7FFFu + ((v.u >> 16) & 1u)) >> 16;
    return (short)r;
}

// P[b][n][k] = sum_c e[b][n][c] * W1[c][k],  e = concat(pos, vel)
__global__ void precompute_P(const float* __restrict__ pos,
                             const float* __restrict__ vel,
                             const float* __restrict__ W1,
                             float* __restrict__ P) {
    const int row = blockIdx.x;      // b*NPTS + n
    const int k   = threadIdx.x;     // 0..63
    const float* pp = pos + row * 3;
    const float* vv = vel + row * 3;
    float acc = 0.f;
    #pragma unroll
    for (int c = 0; c < 3; ++c) acc = fmaf(pp[c], W1[c * HID + k], acc);
    #pragma unroll
    for (int c = 0; c < 3; ++c) acc = fmaf(vv[c], W1[(3 + c) * HID + k], acc);
    P[row * HID + k] = acc;
}

__global__ __launch_bounds__(256) void inet_mfma(
    const float* __restrict__ P,  const float* __restrict__ b1,
    const float* __restrict__ W2, const float* __restrict__ b2,
    const float* __restrict__ W3, float* __restrict__ out) {
    __shared__ float sW2[HID * HID];
    __shared__ float sH[4][HID];

    const int tid  = threadIdx.x;
    const int wv   = tid >> 6;
    const int lane = tid & 63;
    const int c    = lane & 15;   // col / edge-row index within 16
    const int g    = lane >> 4;   // k-group

    for (int idx = tid; idx < HID * HID; idx += 256) sW2[idx] = W2[idx];

    const int b = blockIdx.x >> 10;
    const int i = blockIdx.x & (NPTS - 1);

    // Per-lane k positions: k(kk,h,e) = kk*32 + g*8 + h*4 + e
    const float* Pi = P + ((size_t)(b * NPTS + i)) * HID;
    f32x4 qp[4], qm[4];                 // [kk*2+h]:  b1 -/+ P[i]
    #pragma unroll
    for (int kk = 0; kk < 2; ++kk)
        #pragma unroll
        for (int h = 0; h < 2; ++h) {
            const int k0 = kk * 32 + g * 8 + h * 4;
            f32x4 bb = *(const f32x4*)(b1 + k0);
            f32x4 pp = *(const f32x4*)(Pi + k0);
            qp[kk * 2 + h] = bb - pp;
            qm[kk * 2 + h] = bb + pp;
        }

    f32x4 b2v;
    #pragma unroll
    for (int n = 0; n < 4; ++n) b2v[n] = b2[n * 16 + c];

    __syncthreads();

    // B fragments: Bf[kk*4+n][e] = W2[kk*32 + g*8 + e][n*16 + c]  (bf16)
    bf16x8 Bf[8];
    #pragma unroll
    for (int kk = 0; kk < 2; ++kk)
        #pragma unroll
        for (int n = 0; n < 4; ++n) {
            bf16x8 f;
            #pragma unroll
            for (int e = 0; e < 8; ++e)
                f[e] = f2bf(sW2[(kk * 32 + g * 8 + e) * HID + n * 16 + c]);
            Bf[kk * 4 + n] = f;
        }

    const f32x4 zero = {0.f, 0.f, 0.f, 0.f};
    f32x4 Hp[4], Hm[4];
    #pragma unroll
    for (int n = 0; n < 4; ++n) { Hp[n] = zero; Hm[n] = zero; }

    const float* Pb = P + ((size_t)b * NPTS) * HID;

    for (int t = wv; t < NPTS / 16; t += 4) {
        const int j = t * 16 + c;
        const float* Pr = Pb + (size_t)j * HID;
        f32x4 pj[4];
        #pragma unroll
        for (int kk = 0; kk < 2; ++kk)
            #pragma unroll
            for (int h = 0; h < 2; ++h)
                pj[kk * 2 + h] = *(const f32x4*)(Pr + kk * 32 + g * 8 + h * 4);

        // ---- sign + :  h1 = relu(P[j] - P[i] + b1) = relu(pj + qp) ----
        bf16x8 a0, a1;
        #pragma unroll
        for (int kk = 0; kk < 2; ++kk) {
            bf16x8 a;
            #pragma unroll
            for (int h = 0; h < 2; ++h) {
                f32x4 tv = pj[kk * 2 + h] + qp[kk * 2 + h];
                #pragma unroll
                for (int e = 0; e < 4; ++e) a[h * 4 + e] = f2bf(fmaxf(tv[e], 0.f));
            }
            if (kk == 0) a0 = a; else a1 = a;
        }
        #pragma unroll
        for (int n = 0; n < 4; ++n) {
            f32x4 C = zero;
            C = __builtin_amdgcn_mfma_f32_16x16x32_bf16(a0, Bf[n],     C, 0, 0, 0);
            C = __builtin_amdgcn_mfma_f32_16x16x32_bf16(a1, Bf[4 + n], C, 0, 0, 0);
            #pragma unroll
            for (int r = 0; r < 4; ++r) Hp[n][r] += fmaxf(C[r] + b2v[n], 0.f);
        }

        // ---- sign − :  h1 = relu(-(P[j]-P[i]) + b1) = relu(qm - pj) ----
        #pragma unroll
        for (int kk = 0; kk < 2; ++kk) {
            bf16x8 a;
            #pragma unroll
            for (int h = 0; h < 2; ++h) {
                f32x4 tv = qm[kk * 2 + h] - pj[kk * 2 + h];
                #pragma unroll
                for (int e = 0; e < 4; ++e) a[h * 4 + e] = f2bf(fmaxf(tv[e], 0.f));
            }
            if (kk == 0) a0 = a; else a1 = a;
        }
        #pragma unroll
        for (int n = 0; n < 4; ++n) {
            f32x4 C = zero;
            C = __builtin_amdgcn_mfma_f32_16x16x32_bf16(a0, Bf[n],     C, 0, 0, 0);
            C = __builtin_amdgcn_mfma_f32_16x16x32_bf16(a1, Bf[4 + n], C, 0, 0, 0);
            #pragma unroll
            for (int r = 0; r < 4; ++r) Hm[n][r] += fmaxf(C[r] + b2v[n], 0.f);
        }
    }

    // Wave-level column sums of (Hp - Hm). Sum over rows is layout-invariant.
    float s[4];
    #pragma unroll
    for (int n = 0; n < 4; ++n) {
        float v = (Hp[n][0] - Hm[n][0]) + (Hp[n][1] - Hm[n][1]) +
                  (Hp[n][2] - Hm[n][2]) + (Hp[n][3] - Hm[n][3]);
        v += __shfl_xor(v, 16, 64);
        v += __shfl_xor(v, 32, 64);
        s[n] = v;
    }
    if (lane < 16) {
        #pragma unroll
        for (int n = 0; n < 4; ++n) sH[wv][n * 16 + lane] = s[n];
    }
    __syncthreads();

    if (tid < HID) {
        const int col = tid;
        const float H = sH[0][col] + sH[1][col] + sH[2][col] + sH[3][col];
        float f0 = H * W3[col * 3 + 0];
        float f1 = H * W3[col * 3 + 1];
        float f2 = H * W3[col * 3 + 2];
        #pragma unroll
        for (int off = 32; off; off >>= 1) {
            f0 += __shfl_xor(f0, off, 64);
            f1 += __shfl_xor(f1, off, 64);
            f2 += __shfl_xor(f2, off, 64);
        }
        if (tid == 0) {
            out[(b * NPTS + i) * 3 + 0] = 0.5f * f0;
            out[(b * NPTS + i) * 3 + 1] = 0.5f * f1;
            out[(b * NPTS + i) * 3 + 2] = 0.5f * f2;
        }
    }
}

extern "C" void kernel_launch(void* const* d_in, const int* in_sizes, int n_in,
                              void* d_out, int out_size, void* d_ws, size_t ws_size,
                              hipStream_t stream) {
    const float* pos = (const float*)d_in[0];
    const float* vel = (const float*)d_in[1];
    const float* W1  = (const float*)d_in[2];
    const float* b1  = (const float*)d_in[3];
    const float* W2  = (const float*)d_in[4];
    const float* b2  = (const float*)d_in[5];
    const float* W3  = (const float*)d_in[6];
    const float* b3  = (const float*)d_in[7];   // cancels in antisymmetrization
    (void)b3;
    float* out = (float*)d_out;
    float* P   = (float*)d_ws;                  // NB*NPTS*HID fp32 = 1 MB

    precompute_P<<<dim3(NB * NPTS), dim3(HID), 0, stream>>>(pos, vel, W1, P);
    inet_mfma<<<dim3(NB * NPTS), dim3(256), 0, stream>>>(P, b1, W2, b2, W3, out);
}

// Round 3
// 135.718 us; speedup vs baseline: 37.4533x; 1.1831x over previous
//
#include <hip/hip_runtime.h>

#define NB   4
#define NPTS 1024
#define HID  64

typedef float f32x4  __attribute__((ext_vector_type(4)));
typedef short bf16x8 __attribute__((ext_vector_type(8)));
typedef unsigned int u32;

// HW packed f32->bf16 (RTNE): dst.lo = bf16(lo), dst.hi = bf16(hi). One VALU op.
__device__ inline u32 cvt_pk_bf16(float lo, float hi) {
    u32 r;
    asm("v_cvt_pk_bf16_f32 %0, %1, %2" : "=v"(r) : "v"(lo), "v"(hi));
    return r;
}

union AFrag { bf16x8 v; u32 u[4]; };

// P[b][n][k] = sum_c e[b][n][c] * W1[c][k],  e = concat(pos, vel)
__global__ __launch_bounds__(256) void precompute_P(
    const float* __restrict__ pos, const float* __restrict__ vel,
    const float* __restrict__ W1, float* __restrict__ P) {
    const int t   = blockIdx.x * 256 + threadIdx.x;
    const int row = t >> 6;          // b*NPTS + n
    const int k   = t & 63;
    const float* pp = pos + row * 3;
    const float* vv = vel + row * 3;
    float acc = 0.f;
    #pragma unroll
    for (int c = 0; c < 3; ++c) acc = fmaf(pp[c], W1[c * HID + k], acc);
    #pragma unroll
    for (int c = 0; c < 3; ++c) acc = fmaf(vv[c], W1[(3 + c) * HID + k], acc);
    P[row * HID + k] = acc;
}

__global__ __launch_bounds__(256) void inet_mfma(
    const float* __restrict__ P,  const float* __restrict__ b1,
    const float* __restrict__ W2, const float* __restrict__ b2,
    const float* __restrict__ W3, float* __restrict__ out) {
    __shared__ float sW2[HID * HID];
    __shared__ float sH[4][HID];

    const int tid  = threadIdx.x;
    const int wv   = tid >> 6;
    const int lane = tid & 63;
    const int c    = lane & 15;   // col (output idx / edge-row idx) within 16
    const int g    = lane >> 4;   // k-group

    for (int idx = tid; idx < HID * HID; idx += 256) sW2[idx] = W2[idx];

    const int b = blockIdx.x >> 10;
    const int i = blockIdx.x & (NPTS - 1);

    // Per-lane k positions: k(kk,h,e) = kk*32 + g*8 + h*4 + e
    const float* Pi = P + ((size_t)(b * NPTS + i)) * HID;
    f32x4 qp[4], qm[4];                 // [kk*2+h]:  b1 -/+ P[i]
    #pragma unroll
    for (int kk = 0; kk < 2; ++kk)
        #pragma unroll
        for (int h = 0; h < 2; ++h) {
            const int k0 = kk * 32 + g * 8 + h * 4;
            f32x4 bb = *(const f32x4*)(b1 + k0);
            f32x4 pp = *(const f32x4*)(Pi + k0);
            qp[kk * 2 + h] = bb - pp;
            qm[kk * 2 + h] = bb + pp;
        }

    f32x4 b2v;
    #pragma unroll
    for (int n = 0; n < 4; ++n) b2v[n] = b2[n * 16 + c];

    __syncthreads();

    // B fragments: Bf[kk*4+n][e] = W2[kk*32 + g*8 + e][n*16 + c]  (bf16)
    bf16x8 Bf[8];
    #pragma unroll
    for (int kk = 0; kk < 2; ++kk)
        #pragma unroll
        for (int n = 0; n < 4; ++n) {
            AFrag f;
            #pragma unroll
            for (int e = 0; e < 4; ++e)
                f.u[e] = cvt_pk_bf16(sW2[(kk * 32 + g * 8 + 2 * e) * HID + n * 16 + c],
                                     sW2[(kk * 32 + g * 8 + 2 * e + 1) * HID + n * 16 + c]);
            Bf[kk * 4 + n] = f.v;
        }

    const f32x4 zero = {0.f, 0.f, 0.f, 0.f};
    f32x4 Hp[4], Hm[4];
    #pragma unroll
    for (int n = 0; n < 4; ++n) { Hp[n] = zero; Hm[n] = zero; }

    const float* Pb = P + ((size_t)b * NPTS) * HID;

    for (int t = wv; t < NPTS / 16; t += 4) {
        const int j = t * 16 + c;
        const float* Pr = Pb + (size_t)j * HID;
        f32x4 pj[4];
        #pragma unroll
        for (int kk = 0; kk < 2; ++kk)
            #pragma unroll
            for (int h = 0; h < 2; ++h)
                pj[kk * 2 + h] = *(const f32x4*)(Pr + kk * 32 + g * 8 + h * 4);

        // A fragments for both signs:
        //  +: h1 = relu(P[j] - P[i] + b1) = relu(pj + qp)
        //  -: h1 = relu(-(P[j]-P[i]) + b1) = relu(qm - pj)
        AFrag ap[2], am[2];
        #pragma unroll
        for (int kk = 0; kk < 2; ++kk) {
            float rp[8], rm[8];
            #pragma unroll
            for (int h = 0; h < 2; ++h) {
                f32x4 tp = pj[kk * 2 + h] + qp[kk * 2 + h];
                f32x4 tm = qm[kk * 2 + h] - pj[kk * 2 + h];
                #pragma unroll
                for (int e = 0; e < 4; ++e) {
                    rp[h * 4 + e] = fmaxf(tp[e], 0.f);
                    rm[h * 4 + e] = fmaxf(tm[e], 0.f);
                }
            }
            #pragma unroll
            for (int d = 0; d < 4; ++d) {
                ap[kk].u[d] = cvt_pk_bf16(rp[2 * d], rp[2 * d + 1]);
                am[kk].u[d] = cvt_pk_bf16(rm[2 * d], rm[2 * d + 1]);
            }
        }

        #pragma unroll
        for (int n = 0; n < 4; ++n) {
            f32x4 Cp = {b2v[n], b2v[n], b2v[n], b2v[n]};   // bias folded into C-init
            f32x4 Cm = {b2v[n], b2v[n], b2v[n], b2v[n]};
            Cp = __builtin_amdgcn_mfma_f32_16x16x32_bf16(ap[0].v, Bf[n],     Cp, 0, 0, 0);
            Cp = __builtin_amdgcn_mfma_f32_16x16x32_bf16(ap[1].v, Bf[4 + n], Cp, 0, 0, 0);
            Cm = __builtin_amdgcn_mfma_f32_16x16x32_bf16(am[0].v, Bf[n],     Cm, 0, 0, 0);
            Cm = __builtin_amdgcn_mfma_f32_16x16x32_bf16(am[1].v, Bf[4 + n], Cm, 0, 0, 0);
            #pragma unroll
            for (int r = 0; r < 4; ++r) {
                Hp[n][r] += fmaxf(Cp[r], 0.f);
                Hm[n][r] += fmaxf(Cm[r], 0.f);
            }
        }
    }

    // Wave-level column sums of (Hp - Hm). Sum over rows is layout-invariant.
    float s[4];
    #pragma unroll
    for (int n = 0; n < 4; ++n) {
        float v = (Hp[n][0] - Hm[n][0]) + (Hp[n][1] - Hm[n][1]) +
                  (Hp[n][2] - Hm[n][2]) + (Hp[n][3] - Hm[n][3]);
        v += __shfl_xor(v, 16, 64);
        v += __shfl_xor(v, 32, 64);
        s[n] = v;
    }
    if (lane < 16) {
        #pragma unroll
        for (int n = 0; n < 4; ++n) sH[wv][n * 16 + lane] = s[n];
    }
    __syncthreads();

    if (tid < HID) {
        const int col = tid;
        const float H = sH[0][col] + sH[1][col] + sH[2][col] + sH[3][col];
        float f0 = H * W3[col * 3 + 0];
        float f1 = H * W3[col * 3 + 1];
        float f2 = H * W3[col * 3 + 2];
        #pragma unroll
        for (int off = 32; off; off >>= 1) {
            f0 += __shfl_xor(f0, off, 64);
            f1 += __shfl_xor(f1, off, 64);
            f2 += __shfl_xor(f2, off, 64);
        }
        if (tid == 0) {
            out[(b * NPTS + i) * 3 + 0] = 0.5f * f0;
            out[(b * NPTS + i) * 3 + 1] = 0.5f * f1;
            out[(b * NPTS + i) * 3 + 2] = 0.5f * f2;
        }
    }
}

extern "C" void kernel_launch(void* const* d_in, const int* in_sizes, int n_in,
                              void* d_out, int out_size, void* d_ws, size_t ws_size,
                              hipStream_t stream) {
    const float* pos = (const float*)d_in[0];
    const float* vel = (const float*)d_in[1];
    const float* W1  = (const float*)d_in[2];
    const float* b1  = (const float*)d_in[3];
    const float* W2  = (const float*)d_in[4];
    const float* b2  = (const float*)d_in[5];
    const float* W3  = (const float*)d_in[6];
    const float* b3  = (const float*)d_in[7];   // cancels in antisymmetrization
    (void)b3;
    float* out = (float*)d_out;
    float* P   = (float*)d_ws;                  // NB*NPTS*HID fp32 = 1 MB

    precompute_P<<<dim3(NB * NPTS / 4), dim3(256), 0, stream>>>(pos, vel, W1, P);
    inet_mfma<<<dim3(NB * NPTS), dim3(256), 0, stream>>>(P, b1, W2, b2, W3, out);
}